// Round 4
// baseline (321.173 us; speedup 1.0000x reference)
//
#include <hip/hip_runtime.h>
#include <hip/hip_bf16.h>

// MoE: N=16384 tokens, D=1024, E=8 experts, top-2 routing.
// Round 4: LDS-free, barrier-free grouped GEMM. A fragments gathered straight
// to VGPRs; B pre-permuted to fragment-major so each wave B-load is one
// contiguous 1KB global_load_dwordx4. Block 128x256, 2x2 waves of 64x128.

constexpr int DIMS = 1024;
constexpr int NE   = 8;
constexpr int ROUTER_BLOCKS = 1024;           // 16 tokens per block
constexpr int WCONV_BLOCKS  = NE * DIMS * DIMS / (8 * 256);  // 4096

typedef __attribute__((ext_vector_type(8))) short short8;
typedef __attribute__((ext_vector_type(4))) short short4_t;
typedef __attribute__((ext_vector_type(4))) float f32x4;

__device__ __forceinline__ float b2f(unsigned short u) {
  union { unsigned int i; float f; } x; x.i = ((unsigned)u) << 16; return x.f;
}
__device__ __forceinline__ short f2bs(float f) {
  __hip_bfloat16 h = __float2bfloat16(f);
  return *(short*)&h;
}

// ---------------- prep: router blocks [0,1024) + wconv blocks [1024,5120) ----
// wconv writes wb in FRAGMENT-MAJOR layout: chunk g = ((e*64+nb)*32+kc)*64+l
// holds W[e][n=nb*16+(l&15)][d = kc*32+(l>>4)*8 .. +8] as 8 bf16 (16B).
__global__ __launch_bounds__(256) void prep_kernel(
    const float* __restrict__ x, const float* __restrict__ rw,
    const float* __restrict__ rb, const float* __restrict__ ew,
    __hip_bfloat16* __restrict__ xb, __hip_bfloat16* __restrict__ wb,
    int* __restrict__ counts, int* __restrict__ entries,
    float* __restrict__ gates, int n_tok) {
  const int tid = threadIdx.x;

  if ((int)blockIdx.x >= ROUTER_BLOCKS) {
    unsigned g = (unsigned)(blockIdx.x - ROUTER_BLOCKS) * 256 + tid;
    int l  = g & 63;
    int kc = (g >> 6) & 31;
    int nb = (g >> 11) & 63;
    int e  = g >> 17;
    int row = nb * 16 + (l & 15);
    int kb  = kc * 32 + ((l >> 4) << 3);
    const float4* src = (const float4*)(ew + ((size_t)e << 20) + (size_t)row * DIMS + kb);
    float4 a = src[0], b = src[1];
    union { __hip_bfloat16 h[8]; float4 f; } u;
    u.h[0] = __float2bfloat16(a.x); u.h[1] = __float2bfloat16(a.y);
    u.h[2] = __float2bfloat16(a.z); u.h[3] = __float2bfloat16(a.w);
    u.h[4] = __float2bfloat16(b.x); u.h[5] = __float2bfloat16(b.y);
    u.h[6] = __float2bfloat16(b.z); u.h[7] = __float2bfloat16(b.w);
    ((float4*)wb)[g] = u.f;
    return;
  }

  // ---- router role: 16 tokens/block, wave-per-token, float4 vectorized ----
  __shared__ float s_rw[NE * DIMS];   // 32 KB
  __shared__ int s_cnt[NE], s_base[NE];
  __shared__ int s_e[32];
  __shared__ float s_g[32];
  __shared__ int s_pos[32];

  const float4* rw4g = (const float4*)rw;
  float4* s4 = (float4*)s_rw;
  for (int i = tid; i < NE * DIMS / 4; i += 256) s4[i] = rw4g[i];
  if (tid < NE) s_cnt[tid] = 0;
  __syncthreads();

  const float4* s_rw4 = (const float4*)s_rw;
  const int wave = tid >> 6, lane = tid & 63;
  for (int i = 0; i < 4; ++i) {
    int t = blockIdx.x * 16 + wave * 4 + i;
    const float4* xr = (const float4*)(x + (size_t)t * DIMS);
    short4_t* xw = (short4_t*)(xb + (size_t)t * DIMS);
    float a[NE];
#pragma unroll
    for (int e = 0; e < NE; ++e) a[e] = 0.f;
#pragma unroll
    for (int j = 0; j < 4; ++j) {
      float4 v = xr[lane + j * 64];
      short4_t p;
      p[0] = f2bs(v.x); p[1] = f2bs(v.y); p[2] = f2bs(v.z); p[3] = f2bs(v.w);
      xw[lane + j * 64] = p;
#pragma unroll
      for (int e = 0; e < NE; ++e) {
        float4 w = s_rw4[e * 256 + lane + j * 64];
        a[e] = fmaf(v.x, w.x, fmaf(v.y, w.y, fmaf(v.z, w.z, fmaf(v.w, w.w, a[e]))));
      }
    }
#pragma unroll
    for (int off = 32; off > 0; off >>= 1) {
#pragma unroll
      for (int e = 0; e < NE; ++e) a[e] += __shfl_xor(a[e], off, 64);
    }
    if (lane == 0) {
      float l[NE];
#pragma unroll
      for (int e = 0; e < NE; ++e) l[e] = a[e] + rb[e];
      int e0 = 0;
#pragma unroll
      for (int e = 1; e < NE; ++e) if (l[e] > l[e0]) e0 = e;
      int e1 = (e0 == 0) ? 1 : 0;
#pragma unroll
      for (int e = 0; e < NE; ++e) if (e != e0 && l[e] > l[e1]) e1 = e;
      float r = expf(l[e1] - l[e0]);   // <= 1
      float g0 = 1.f / (1.f + r);
      float g1 = 1.f - g0;
      int ai = (wave * 4 + i) * 2;
      int p0 = atomicAdd(&s_cnt[e0], 1);
      int p1 = atomicAdd(&s_cnt[e1], 1);
      s_e[ai] = e0; s_g[ai] = g0; s_pos[ai] = p0;
      s_e[ai + 1] = e1; s_g[ai + 1] = g1; s_pos[ai + 1] = p1;
    }
  }
  __syncthreads();
  if (tid < NE) s_base[tid] = atomicAdd(&counts[tid], s_cnt[tid]);
  __syncthreads();
  if (tid < 32) {
    int e = s_e[tid];
    int p = s_base[e] + s_pos[tid];
    int tok = blockIdx.x * 16 + (tid >> 1);
    entries[e * n_tok + p] = (tok << 1) | (tid & 1);  // token*2 + slot
    gates[e * n_tok + p] = s_g[tid];
  }
}

// ---------------- grouped gathered GEMM: LDS-free, barrier-free ----------------
// Block 128 rows x 256 cols; waves 2x2, each wave 64x128 = 4x8 of 16x16x32 bf16.
// A: per-lane gather loads from xb (16 rows x 16B per instr).
// B: fragment-major wb -> one contiguous 1KB load per fragment.
__global__ __launch_bounds__(256, 2) void moe_gemm(
    const __hip_bfloat16* __restrict__ xb, const __hip_bfloat16* __restrict__ wb,
    const float* __restrict__ eb, const int* __restrict__ counts,
    const int* __restrict__ entries, const float* __restrict__ gates,
    __hip_bfloat16* __restrict__ y, int n_tok) {
  // map blockIdx.y -> (expert, row-tile of 128) from device-side counts
  int e = -1, rt = 0, cnt = 0, acc_t = 0;
#pragma unroll
  for (int i = 0; i < NE; ++i) {
    int c = counts[i];
    int t = (c + 127) >> 7;
    if (e < 0 && (int)blockIdx.y < acc_t + t) { e = i; rt = (int)blockIdx.y - acc_t; cnt = c; }
    acc_t += t;
  }
  if (e < 0) return;

  const int tid = threadIdx.x;
  const int lane = tid & 63, wave = tid >> 6;
  const int row0 = rt * 128;
  const int n0 = blockIdx.x * 256;
  const int wm = (wave & 1) * 64, wn = (wave >> 1) * 128;
  const int fr = lane & 15, quad = lane >> 4;

  // A row pointers: lane's row for m-block mb is row0+wm+mb*16+fr;
  // lane's 16B chunk within a BK=32 slab is slab*4 + quad (in short8 units).
  const short8* ap[4];
#pragma unroll
  for (int mb = 0; mb < 4; ++mb) {
    int gr = row0 + wm + mb * 16 + fr;
    int ent = (gr < cnt) ? entries[e * n_tok + gr] : 0;
    ap[mb] = (const short8*)(xb + (size_t)(ent >> 1) * DIMS) + quad;
  }

  // B fragment index: wb8[((e*64 + nb)*32 + kc)*64 + lane], nb = (n0+wn)/16 + nt
  const short8* wb8 = (const short8*)wb;
  const size_t bbase = ((((size_t)e * 64 + ((n0 + wn) >> 4)) * 32) << 6) + lane;

  f32x4 acc[4][8] = {};

#pragma unroll 2
  for (int kc = 0; kc < 32; ++kc) {
    short8 af[4], bf[8];
#pragma unroll
    for (int mb = 0; mb < 4; ++mb) af[mb] = ap[mb][kc * 4];
#pragma unroll
    for (int nt = 0; nt < 8; ++nt) bf[nt] = wb8[bbase + ((size_t)nt << 11) + (kc << 6)];
#pragma unroll
    for (int mt = 0; mt < 4; ++mt)
#pragma unroll
      for (int nt = 0; nt < 8; ++nt)
        acc[mt][nt] = __builtin_amdgcn_mfma_f32_16x16x32_bf16(af[mt], bf[nt], acc[mt][nt], 0, 0, 0);
  }

  // epilogue: C/D layout col=lane&15, row=(lane>>4)*4+reg. Store gated y (bf16).
  float bias[8];
#pragma unroll
  for (int nt = 0; nt < 8; ++nt) bias[nt] = eb[e * DIMS + n0 + wn + nt * 16 + fr];
#pragma unroll
  for (int mt = 0; mt < 4; ++mt) {
#pragma unroll
    for (int r = 0; r < 4; ++r) {
      int m = wm + mt * 16 + quad * 4 + r;
      int gr = row0 + m;
      if (gr < cnt) {
        int ent = entries[e * n_tok + gr];
        float g = gates[e * n_tok + gr];
        __hip_bfloat16* yp = y + (size_t)ent * DIMS + n0 + wn + fr;
#pragma unroll
        for (int nt = 0; nt < 8; ++nt)
          yp[nt * 16] = __float2bfloat16(g * (acc[mt][nt][r] + bias[nt]));
      }
    }
  }
}

// ---------------- combine: out[n] = y[n,0] + y[n,1] ----------------
__global__ __launch_bounds__(256) void combine_kernel(const __hip_bfloat16* __restrict__ y,
                                                      float* __restrict__ out) {
  size_t idx = (size_t)blockIdx.x * 256 + threadIdx.x;  // one 8-wide chunk
  size_t n = idx >> 7;
  int c = (int)(idx & 127) << 3;
  short8 v0 = *(const short8*)(y + (n * 2) * DIMS + c);
  short8 v1 = *(const short8*)(y + (n * 2 + 1) * DIMS + c);
  float4 o0, o1;
  o0.x = b2f((unsigned short)v0[0]) + b2f((unsigned short)v1[0]);
  o0.y = b2f((unsigned short)v0[1]) + b2f((unsigned short)v1[1]);
  o0.z = b2f((unsigned short)v0[2]) + b2f((unsigned short)v1[2]);
  o0.w = b2f((unsigned short)v0[3]) + b2f((unsigned short)v1[3]);
  o1.x = b2f((unsigned short)v0[4]) + b2f((unsigned short)v1[4]);
  o1.y = b2f((unsigned short)v0[5]) + b2f((unsigned short)v1[5]);
  o1.z = b2f((unsigned short)v0[6]) + b2f((unsigned short)v1[6]);
  o1.w = b2f((unsigned short)v0[7]) + b2f((unsigned short)v1[7]);
  float* op = out + n * DIMS + c;
  ((float4*)op)[0] = o0;
  ((float4*)op)[1] = o1;
}

extern "C" void kernel_launch(void* const* d_in, const int* in_sizes, int n_in,
                              void* d_out, int out_size, void* d_ws, size_t ws_size,
                              hipStream_t stream) {
  const float* x  = (const float*)d_in[0];
  const float* rw = (const float*)d_in[1];
  const float* rb = (const float*)d_in[2];
  const float* ew = (const float*)d_in[3];
  const float* eb = (const float*)d_in[4];
  float* out = (float*)d_out;
  const int n_tok = in_sizes[0] / DIMS;  // 16384

  // workspace layout
  char* ws = (char*)d_ws;
  size_t off = 0;
  int* counts = (int*)ws;                      off += 256;
  __hip_bfloat16* xb = (__hip_bfloat16*)(ws + off); off += (size_t)n_tok * DIMS * 2;
  __hip_bfloat16* wb = (__hip_bfloat16*)(ws + off); off += (size_t)NE * DIMS * DIMS * 2;
  int*   entries = (int*)(ws + off);           off += (size_t)NE * n_tok * 4;
  float* gates   = (float*)(ws + off);         off += (size_t)NE * n_tok * 4;
  __hip_bfloat16* y = (__hip_bfloat16*)(ws + off); off += (size_t)n_tok * 2 * DIMS * 2;
  if (ws_size < off) return;  // signature: output stays exactly zero

  hipMemsetAsync(counts, 0, 256, stream);
  prep_kernel<<<ROUTER_BLOCKS + WCONV_BLOCKS, 256, 0, stream>>>(
      x, rw, rb, ew, xb, wb, counts, entries, gates, n_tok);
  dim3 g(DIMS / 256, 2 * n_tok / 128 + NE);
  moe_gemm<<<g, 256, 0, stream>>>(xb, wb, eb, counts, entries, gates, y, n_tok);
  combine_kernel<<<(unsigned)((size_t)n_tok * DIMS / 8 / 256), 256, 0, stream>>>(y, out);
}

// Round 5
// 273.047 us; speedup vs baseline: 1.1763x; 1.1763x over previous
//
#include <hip/hip_runtime.h>
#include <hip/hip_bf16.h>

// MoE: N=16384 tokens, D=1024, E=8 experts, top-2 routing.
// R5: atomic-free 3-phase routing (prep -> scan -> scatter); gemm with
// XCD-affine block mapping (bid%8 = XCD owns contiguous row-slice), A via
// global_load_lds (swizzled, 8KB), B direct from fragment-major wb.

constexpr int DIMS = 1024;
constexpr int NE   = 8;
constexpr int ROUTER_BLOCKS = 1024;           // 16 tokens per block
constexpr int WCONV_BLOCKS  = NE * DIMS * DIMS / (8 * 256);  // 4096
constexpr int RT_PER_XCD = 33;                // 33*8 = 264 >= 256+8 row-tiles

typedef __attribute__((ext_vector_type(8))) short short8;
typedef __attribute__((ext_vector_type(4))) short short4_t;
typedef __attribute__((ext_vector_type(4))) float f32x4;

typedef const __attribute__((address_space(1))) void* gp_t;
typedef __attribute__((address_space(3))) void* sp_t;

__device__ __forceinline__ float b2f(unsigned short u) {
  union { unsigned int i; float f; } x; x.i = ((unsigned)u) << 16; return x.f;
}
__device__ __forceinline__ short f2bs(float f) {
  __hip_bfloat16 h = __float2bfloat16(f);
  return *(short*)&h;
}

// ---------------- prep: router blocks [0,1024) + wconv blocks [1024,5120) ----
// wconv writes wb FRAGMENT-MAJOR: chunk g = ((e*64+nb)*32+kc)*64+l holds
// W[e][n=nb*16+(l&15)][d = kc*32+(l>>4)*8 .. +8] as 8 bf16 (16B).
// router: NO global atomics — writes per-block counts + per-slot meta.
__global__ __launch_bounds__(256) void prep_kernel(
    const float* __restrict__ x, const float* __restrict__ rw,
    const float* __restrict__ rb, const float* __restrict__ ew,
    __hip_bfloat16* __restrict__ xb, __hip_bfloat16* __restrict__ wb,
    int* __restrict__ blk_cnt, int* __restrict__ tmp_meta,
    float* __restrict__ tmp_gate, int n_tok) {
  const int tid = threadIdx.x;

  if ((int)blockIdx.x >= ROUTER_BLOCKS) {
    unsigned g = (unsigned)(blockIdx.x - ROUTER_BLOCKS) * 256 + tid;
    int l  = g & 63;
    int kc = (g >> 6) & 31;
    int nb = (g >> 11) & 63;
    int e  = g >> 17;
    int row = nb * 16 + (l & 15);
    int kb  = kc * 32 + ((l >> 4) << 3);
    const float4* src = (const float4*)(ew + ((size_t)e << 20) + (size_t)row * DIMS + kb);
    float4 a = src[0], b = src[1];
    union { __hip_bfloat16 h[8]; float4 f; } u;
    u.h[0] = __float2bfloat16(a.x); u.h[1] = __float2bfloat16(a.y);
    u.h[2] = __float2bfloat16(a.z); u.h[3] = __float2bfloat16(a.w);
    u.h[4] = __float2bfloat16(b.x); u.h[5] = __float2bfloat16(b.y);
    u.h[6] = __float2bfloat16(b.z); u.h[7] = __float2bfloat16(b.w);
    ((float4*)wb)[g] = u.f;
    return;
  }

  // ---- router role: 16 tokens/block, wave-per-token, float4 vectorized ----
  __shared__ float s_rw[NE * DIMS];   // 32 KB
  __shared__ int s_cnt[NE];
  __shared__ int s_e[32];
  __shared__ float s_g[32];
  __shared__ int s_pos[32];

  const float4* rw4g = (const float4*)rw;
  float4* s4 = (float4*)s_rw;
  for (int i = tid; i < NE * DIMS / 4; i += 256) s4[i] = rw4g[i];
  if (tid < NE) s_cnt[tid] = 0;
  __syncthreads();

  const float4* s_rw4 = (const float4*)s_rw;
  const int wave = tid >> 6, lane = tid & 63;
  for (int i = 0; i < 4; ++i) {
    int t = blockIdx.x * 16 + wave * 4 + i;
    const float4* xr = (const float4*)(x + (size_t)t * DIMS);
    short4_t* xw = (short4_t*)(xb + (size_t)t * DIMS);
    float a[NE];
#pragma unroll
    for (int e = 0; e < NE; ++e) a[e] = 0.f;
#pragma unroll
    for (int j = 0; j < 4; ++j) {
      float4 v = xr[lane + j * 64];
      short4_t p;
      p[0] = f2bs(v.x); p[1] = f2bs(v.y); p[2] = f2bs(v.z); p[3] = f2bs(v.w);
      xw[lane + j * 64] = p;
#pragma unroll
      for (int e = 0; e < NE; ++e) {
        float4 w = s_rw4[e * 256 + lane + j * 64];
        a[e] = fmaf(v.x, w.x, fmaf(v.y, w.y, fmaf(v.z, w.z, fmaf(v.w, w.w, a[e]))));
      }
    }
#pragma unroll
    for (int off = 32; off > 0; off >>= 1) {
#pragma unroll
      for (int e = 0; e < NE; ++e) a[e] += __shfl_xor(a[e], off, 64);
    }
    if (lane == 0) {
      float l[NE];
#pragma unroll
      for (int e = 0; e < NE; ++e) l[e] = a[e] + rb[e];
      int e0 = 0;
#pragma unroll
      for (int e = 1; e < NE; ++e) if (l[e] > l[e0]) e0 = e;
      int e1 = (e0 == 0) ? 1 : 0;
#pragma unroll
      for (int e = 0; e < NE; ++e) if (e != e0 && l[e] > l[e1]) e1 = e;
      float r = expf(l[e1] - l[e0]);   // <= 1
      float g0 = 1.f / (1.f + r);
      float g1 = 1.f - g0;
      int ai = (wave * 4 + i) * 2;
      int p0 = atomicAdd(&s_cnt[e0], 1);   // LDS atomic only
      int p1 = atomicAdd(&s_cnt[e1], 1);
      s_e[ai] = e0; s_g[ai] = g0; s_pos[ai] = p0;
      s_e[ai + 1] = e1; s_g[ai + 1] = g1; s_pos[ai + 1] = p1;
    }
  }
  __syncthreads();
  if (tid < NE) blk_cnt[blockIdx.x * NE + tid] = s_cnt[tid];
  if (tid < 32) {
    int s = blockIdx.x * 32 + tid;
    tmp_meta[s] = s_e[tid] | (s_pos[tid] << 3);
    tmp_gate[s] = s_g[tid];
  }
}

// ---------------- scan: exclusive prefix of blk_cnt per expert ----------------
// one block, 512 threads: wave e scans 1024 blocks for expert e.
__global__ __launch_bounds__(512) void scan_kernel(
    const int* __restrict__ blk_cnt, int* __restrict__ blk_base,
    int* __restrict__ counts) {
  const int e = threadIdx.x >> 6, lane = threadIdx.x & 63;
  int running = 0;
  for (int c = 0; c < ROUTER_BLOCKS / 64; ++c) {
    int v = blk_cnt[(c * 64 + lane) * NE + e];
    int incl = v;
#pragma unroll
    for (int off = 1; off < 64; off <<= 1) {
      int t = __shfl_up(incl, off, 64);
      if (lane >= off) incl += t;
    }
    blk_base[(c * 64 + lane) * NE + e] = running + incl - v;
    running += __shfl(incl, 63, 64);
  }
  if (lane == 0) counts[e] = running;
}

// ---------------- scatter: place entries/gates ----------------
__global__ __launch_bounds__(256) void scatter_kernel(
    const int* __restrict__ tmp_meta, const float* __restrict__ tmp_gate,
    const int* __restrict__ blk_base, int* __restrict__ entries,
    float* __restrict__ gates, int n_tok) {
  int s = blockIdx.x * 256 + threadIdx.x;       // slot in [0, 2*n_tok)
  int meta = tmp_meta[s];
  int e = meta & 7, pos = meta >> 3;
  int p = blk_base[(s >> 5) * NE + e] + pos;
  entries[e * n_tok + p] = ((s >> 1) << 1) | (s & 1);   // token*2 + slot parity
  gates[e * n_tok + p] = tmp_gate[s];
}

// ---------------- grouped gathered GEMM ----------------
// 128x128 tile, BK=32; 4 waves (2x2) of 64x64 = 4x4 of 16x16x32 bf16.
// bid: xcd=bid%8 owns row-tiles [33*xcd, 33*xcd+33), rt-major over 8 col-tiles
// (A tile L2-resident across cts; B ~1 expert/XCD L2-resident).
// A: global_load_lds with XOR chunk swizzle. B: direct fragment-major global.
__global__ __launch_bounds__(256, 4) void moe_gemm(
    const __hip_bfloat16* __restrict__ xb, const __hip_bfloat16* __restrict__ wb,
    const float* __restrict__ eb, const int* __restrict__ counts,
    const int* __restrict__ entries, const float* __restrict__ gates,
    __hip_bfloat16* __restrict__ y, int n_tok) {
  const int xcd = blockIdx.x & 7;
  const int j = blockIdx.x >> 3;
  const int ct = j & 7;
  const int virt = xcd * RT_PER_XCD + (j >> 3);   // virtual row-tile id

  // map virt -> (expert, row-tile) from device-side counts
  int e = -1, rt = 0, cnt = 0, acc_t = 0;
#pragma unroll
  for (int i = 0; i < NE; ++i) {
    int c = counts[i];
    int t = (c + 127) >> 7;
    if (e < 0 && virt < acc_t + t) { e = i; rt = virt - acc_t; cnt = c; }
    acc_t += t;
  }
  if (e < 0) return;

  __shared__ __hip_bfloat16 As[128 * 32];  // 8 KB

  const int tid = threadIdx.x;
  const int lane = tid & 63, wave = tid >> 6;
  const int row0 = rt * 128;
  const int n0 = ct * 128;

  // A staging: thread t -> LDS slots t, t+256 (16B chunks); slot (srow, q)
  // holds global chunk kcs = q ^ (srow&3).
  const int srow = tid >> 2;
  const int kcs = (tid & 3) ^ (srow & 3);
  const int kcol = kcs * 8;
  int gr0 = row0 + srow, gr1 = row0 + srow + 64;
  int ent0 = (gr0 < cnt) ? entries[e * n_tok + gr0] : 0;
  int ent1 = (gr1 < cnt) ? entries[e * n_tok + gr1] : 0;
  const __hip_bfloat16* ap0 = xb + (size_t)(ent0 >> 1) * DIMS + kcol;
  const __hip_bfloat16* ap1 = xb + (size_t)(ent1 >> 1) * DIMS + kcol;

  const int wm = (wave & 1) * 64, wn = (wave >> 1) * 64;
  const int fr = lane & 15, quad = lane >> 4;
  const int swo = (quad ^ (fr & 3)) * 8;   // swizzled read offset

  // B fragment-major: chunk g = ((e*64+nb)*32+kc)*64 + lane
  const short8* wb8 = (const short8*)wb;
  const size_t bbase = (((size_t)e * 64 + ((n0 + wn) >> 4)) * 32) * 64 + lane;

  f32x4 acc[4][4] = {};

  for (int ks = 0; ks < 32; ++ks) {
    __builtin_amdgcn_global_load_lds((gp_t)(ap0 + ks * 32), (sp_t)(As + tid * 8), 16, 0, 0);
    __builtin_amdgcn_global_load_lds((gp_t)(ap1 + ks * 32), (sp_t)(As + (tid + 256) * 8), 16, 0, 0);
    short8 bf[4];
#pragma unroll
    for (int nt = 0; nt < 4; ++nt)
      bf[nt] = wb8[bbase + (size_t)nt * 2048 + ks * 64];
    __syncthreads();
    short8 af[4];
#pragma unroll
    for (int mt = 0; mt < 4; ++mt)
      af[mt] = *(const short8*)&As[(wm + mt * 16 + fr) * 32 + swo];
#pragma unroll
    for (int mt = 0; mt < 4; ++mt)
#pragma unroll
      for (int nt = 0; nt < 4; ++nt)
        acc[mt][nt] = __builtin_amdgcn_mfma_f32_16x16x32_bf16(af[mt], bf[nt], acc[mt][nt], 0, 0, 0);
    __syncthreads();
  }

  // epilogue: C/D layout col=lane&15, row=(lane>>4)*4+reg. Store gated y (bf16).
  float bias[4];
#pragma unroll
  for (int nt = 0; nt < 4; ++nt) bias[nt] = eb[e * DIMS + n0 + wn + nt * 16 + fr];
#pragma unroll
  for (int mt = 0; mt < 4; ++mt) {
#pragma unroll
    for (int r = 0; r < 4; ++r) {
      int m = wm + mt * 16 + quad * 4 + r;
      int gr = row0 + m;
      if (gr < cnt) {
        int ent = entries[e * n_tok + gr];
        float g = gates[e * n_tok + gr];
        __hip_bfloat16* yp = y + (size_t)ent * DIMS + n0 + wn + fr;
#pragma unroll
        for (int nt = 0; nt < 4; ++nt)
          yp[nt * 16] = __float2bfloat16(g * (acc[mt][nt][r] + bias[nt]));
      }
    }
  }
}

// ---------------- combine: out[n] = y[n,0] + y[n,1] ----------------
__global__ __launch_bounds__(256) void combine_kernel(const __hip_bfloat16* __restrict__ y,
                                                      float* __restrict__ out) {
  size_t idx = (size_t)blockIdx.x * 256 + threadIdx.x;  // one 8-wide chunk
  size_t n = idx >> 7;
  int c = (int)(idx & 127) << 3;
  short8 v0 = *(const short8*)(y + (n * 2) * DIMS + c);
  short8 v1 = *(const short8*)(y + (n * 2 + 1) * DIMS + c);
  float4 o0, o1;
  o0.x = b2f((unsigned short)v0[0]) + b2f((unsigned short)v1[0]);
  o0.y = b2f((unsigned short)v0[1]) + b2f((unsigned short)v1[1]);
  o0.z = b2f((unsigned short)v0[2]) + b2f((unsigned short)v1[2]);
  o0.w = b2f((unsigned short)v0[3]) + b2f((unsigned short)v1[3]);
  o1.x = b2f((unsigned short)v0[4]) + b2f((unsigned short)v1[4]);
  o1.y = b2f((unsigned short)v0[5]) + b2f((unsigned short)v1[5]);
  o1.z = b2f((unsigned short)v0[6]) + b2f((unsigned short)v1[6]);
  o1.w = b2f((unsigned short)v0[7]) + b2f((unsigned short)v1[7]);
  float* op = out + n * DIMS + c;
  ((float4*)op)[0] = o0;
  ((float4*)op)[1] = o1;
}

extern "C" void kernel_launch(void* const* d_in, const int* in_sizes, int n_in,
                              void* d_out, int out_size, void* d_ws, size_t ws_size,
                              hipStream_t stream) {
  const float* x  = (const float*)d_in[0];
  const float* rw = (const float*)d_in[1];
  const float* rb = (const float*)d_in[2];
  const float* ew = (const float*)d_in[3];
  const float* eb = (const float*)d_in[4];
  float* out = (float*)d_out;
  const int n_tok = in_sizes[0] / DIMS;  // 16384
  const int n_slot = 2 * n_tok;

  // workspace layout
  char* ws = (char*)d_ws;
  size_t off = 0;
  int* counts = (int*)ws;                      off += 256;
  int* blk_cnt = (int*)(ws + off);             off += (size_t)ROUTER_BLOCKS * NE * 4;
  int* blk_base = (int*)(ws + off);            off += (size_t)ROUTER_BLOCKS * NE * 4;
  int* tmp_meta = (int*)(ws + off);            off += (size_t)n_slot * 4;
  float* tmp_gate = (float*)(ws + off);        off += (size_t)n_slot * 4;
  __hip_bfloat16* xb = (__hip_bfloat16*)(ws + off); off += (size_t)n_tok * DIMS * 2;
  __hip_bfloat16* wb = (__hip_bfloat16*)(ws + off); off += (size_t)NE * DIMS * DIMS * 2;
  int*   entries = (int*)(ws + off);           off += (size_t)NE * n_tok * 4;
  float* gates   = (float*)(ws + off);         off += (size_t)NE * n_tok * 4;
  __hip_bfloat16* y = (__hip_bfloat16*)(ws + off); off += (size_t)n_slot * DIMS * 2;
  if (ws_size < off) return;  // signature: output stays exactly zero

  prep_kernel<<<ROUTER_BLOCKS + WCONV_BLOCKS, 256, 0, stream>>>(
      x, rw, rb, ew, xb, wb, blk_cnt, tmp_meta, tmp_gate, n_tok);
  scan_kernel<<<1, 512, 0, stream>>>(blk_cnt, blk_base, counts);
  scatter_kernel<<<n_slot / 256, 256, 0, stream>>>(
      tmp_meta, tmp_gate, blk_base, entries, gates, n_tok);
  moe_gemm<<<8 * RT_PER_XCD * 8, 256, 0, stream>>>(
      xb, wb, eb, counts, entries, gates, y, n_tok);
  combine_kernel<<<(unsigned)((size_t)n_tok * DIMS / 8 / 256), 256, 0, stream>>>(y, out);
}